// Round 7
// baseline (246.783 us; speedup 1.0000x reference)
//
#include <hip/hip_runtime.h>
#include <hip/hip_bf16.h>

// MultiHeadAttention: B=2, S=2048, D=1024, H=16, DK=64
// Round 7: revert t-split (single-pass flash, no reduce kernel); swapped MFMA
// orientation in proj/out (A=W, B=X) so C/D rows = features -> packed uint2
// stores for q/k heads and float4 stores in gemm_out. XCD swizzles kept.
// Workspace: qb@0 kb@8 vb@16 Wcat@24(6M) Wob@30 mbits@32 qhd@33 khd@41
//            vtd@49 oc@57  (MiB offsets)

using bf16x8 = __attribute__((ext_vector_type(8))) short;
using f32x4  = __attribute__((ext_vector_type(4))) float;

constexpr int Bc = 2, Sc = 2048, Dc = 1024, Hc = 16, DKc = 64;
constexpr int Mc = Bc * Sc;  // 4096
#define QSCALE 0.18033688011112042f  // log2(e)/sqrt(DK), folded into Q proj

__device__ __forceinline__ void lds_load16(const void* g, void* l) {
  __builtin_amdgcn_global_load_lds(
      (const __attribute__((address_space(1))) unsigned int*)g,
      (__attribute__((address_space(3))) unsigned int*)l, 16, 0, 0);
}

#if __has_builtin(__builtin_amdgcn_exp2f)
__device__ __forceinline__ float exp2_fast(float x) { return __builtin_amdgcn_exp2f(x); }
#else
__device__ __forceinline__ float exp2_fast(float x) {
  float r;
  asm("v_exp_f32 %0, %1\n\ts_nop 0" : "=v"(r) : "v"(x));
  return r;
}
#endif

// truncating bf16x2 pack: [hi16(b) : hi16(a)] — one v_perm_b32
__device__ __forceinline__ unsigned pack_trunc(float a, float b) {
  return __builtin_amdgcn_perm(__float_as_uint(b), __float_as_uint(a), 0x07060302u);
}

// RNE pack (epilogues)
__device__ __forceinline__ unsigned pack2bf(float a, float b) {
  union { __hip_bfloat16 h; unsigned short s; } ua, ub;
  ua.h = __float2bfloat16(a);
  ub.h = __float2bfloat16(b);
  return (unsigned)ua.s | ((unsigned)ub.s << 16);
}

// ---------------- prep: fused casts + mask pack ----------------
// blocks [0,12288): cast q/k/v; [12288,16384): cast Wq/Wk/Wv/Wo;
// [16384,32768): mask -> bit matrix @32MB.
__global__ void prep(const float* __restrict__ q, const float* __restrict__ k,
                     const float* __restrict__ v, const int* __restrict__ mask,
                     const float* __restrict__ Wq, const float* __restrict__ Wk,
                     const float* __restrict__ Wv, const float* __restrict__ Wo,
                     char* __restrict__ ws) {
  const size_t MB = 1024 * 1024;
  int blk = blockIdx.x;
  if (blk < 12288) {
    int which = blk >> 12;
    int i = (((blk & 4095) << 8) + threadIdx.x) * 4;
    const float* s = which == 0 ? q : (which == 1 ? k : v);
    __hip_bfloat16* d = (__hip_bfloat16*)(ws + (size_t)which * 8 * MB);
    float4 x = *(const float4*)&s[i];
    uint2 pk = {pack2bf(x.x, x.y), pack2bf(x.z, x.w)};
    *(uint2*)&d[i] = pk;
  } else if (blk < 16384) {
    int bb = blk - 12288;
    int which = bb >> 10;
    int i = (((bb & 1023) << 8) + threadIdx.x) * 4;
    const float* s = which == 0 ? Wq : (which == 1 ? Wk : (which == 2 ? Wv : Wo));
    __hip_bfloat16* d = which < 3 ? (__hip_bfloat16*)(ws + (24 + 2 * which) * MB)
                                  : (__hip_bfloat16*)(ws + 30 * MB);
    float4 x = *(const float4*)&s[i];
    uint2 pk = {pack2bf(x.x, x.y), pack2bf(x.z, x.w)};
    *(uint2*)&d[i] = pk;
  } else {
    int i = ((blk - 16384) << 8) + threadIdx.x;
    unsigned long long bal = __ballot(mask[i] != 0);
    if ((threadIdx.x & 63) == 0)
      ((unsigned long long*)(ws + 32 * MB))[i >> 6] = bal;
  }
}

// ---------------- fused QKV projection (swapped orientation) ----------------
// A = Wcat rows (features), B = X rows (s). C/D: col=lane&15 -> s,
// row=quad*4+r -> feature. flat grid 768, XCD swizzle.
__global__ __launch_bounds__(256, 3) void proj_qkv(
    const __hip_bfloat16* __restrict__ qb, const __hip_bfloat16* __restrict__ kb,
    const __hip_bfloat16* __restrict__ vb, const __hip_bfloat16* __restrict__ Wcat,
    const float* __restrict__ bq, const float* __restrict__ bk,
    const float* __restrict__ bv, __hip_bfloat16* __restrict__ qhd,
    __hip_bfloat16* __restrict__ khd, __hip_bfloat16* __restrict__ vtd) {
  __shared__ __align__(16) __hip_bfloat16 As[128 * 64];  // W tile (128 feats)
  __shared__ __align__(16) __hip_bfloat16 Bs[128 * 64];  // X tile (128 s)
  const int tid = threadIdx.x;
  const int f = blockIdx.x, g = f >> 3;
  const int m0 = ((f & 7) * 4 + g / 24) * 128;  // s block
  const int n0 = (g % 24) * 128;                // feature block (0..3072)
  const int which = n0 >> 10, nl0 = n0 & 1023;
  const __hip_bfloat16* X = which == 0 ? qb : (which == 1 ? kb : vb);
  const float* bias = which == 0 ? bq : (which == 1 ? bk : bv);
  const int w = tid >> 6, lane = tid & 63, ln = lane & 15, quad = lane >> 4;
  const int swz = ((lane & 7) ^ (lane >> 3)) * 8;
  const int rk0 = ln * 128 + ((quad ^ (ln & 7)) * 16);
  const int rk1 = ln * 128 + (((quad + 4) ^ (ln & 7)) * 16);
  const int aoff = (n0 + w * 32 + (lane >> 3)) * 1024 + swz;  // W source
  const int boff = (m0 + w * 32 + (lane >> 3)) * 1024 + swz;  // X source
  char* aF = (char*)As + (w >> 1) * 8192;  // wave A-sub: 64 features
  char* bF = (char*)Bs + (w & 1) * 8192;   // wave B-sub: 64 s
  char* aDst = (char*)As + w * 4096 + lane * 16;
  char* bDst = (char*)Bs + w * 4096 + lane * 16;
  f32x4 acc[4][4] = {};  // [i: feature 16-blk][j: s 16-blk]
  int ko = 0;
  for (int kb64 = 0; kb64 < 16; ++kb64, ko += 64) {
#pragma unroll
    for (int i = 0; i < 4; ++i) {
      lds_load16(&Wcat[aoff + i * 8192 + ko], aDst + i * 1024);
      lds_load16(&X[boff + i * 8192 + ko], bDst + i * 1024);
    }
    __syncthreads();
    bf16x8 af[4][2], bf[4][2];
#pragma unroll
    for (int i = 0; i < 4; ++i) {
      af[i][0] = *(bf16x8*)(aF + i * 2048 + rk0);
      af[i][1] = *(bf16x8*)(aF + i * 2048 + rk1);
      bf[i][0] = *(bf16x8*)(bF + i * 2048 + rk0);
      bf[i][1] = *(bf16x8*)(bF + i * 2048 + rk1);
    }
#pragma unroll
    for (int i = 0; i < 4; ++i)
#pragma unroll
      for (int j = 0; j < 4; ++j) {
        acc[i][j] = __builtin_amdgcn_mfma_f32_16x16x32_bf16(af[i][0], bf[j][0],
                                                            acc[i][j], 0, 0, 0);
        acc[i][j] = __builtin_amdgcn_mfma_f32_16x16x32_bf16(af[i][1], bf[j][1],
                                                            acc[i][j], 0, 0, 0);
      }
    __syncthreads();
  }
  // epilogue: col(ln)=s, row(quad*4+r)=feature -> 4 consecutive dk per lane
  const int wA = (w >> 1) * 64, wB = (w & 1) * 64;
#pragma unroll
  for (int i = 0; i < 4; ++i) {
    int nfb = nl0 + wA + i * 16 + quad * 4;  // 4 consecutive features
    float4 b4 = *(const float4*)&bias[nfb];
    int h = nfb >> 6, dk0 = nfb & 63;
#pragma unroll
    for (int j = 0; j < 4; ++j) {
      int sg = m0 + wB + j * 16 + ln;
      int b = sg >> 11, s = sg & 2047;
      float vv[4] = {acc[i][j][0] + b4.x, acc[i][j][1] + b4.y,
                     acc[i][j][2] + b4.z, acc[i][j][3] + b4.w};
      if (which == 0) {
        uint2 pk = {pack2bf(vv[0] * QSCALE, vv[1] * QSCALE),
                    pack2bf(vv[2] * QSCALE, vv[3] * QSCALE)};
        *(uint2*)&qhd[(((size_t)(b * Hc + h) * Sc + s) * DKc) + dk0] = pk;
      } else if (which == 1) {
        uint2 pk = {pack2bf(vv[0], vv[1]), pack2bf(vv[2], vv[3])};
        *(uint2*)&khd[(((size_t)(b * Hc + h) * Sc + s) * DKc) + dk0] = pk;
      } else {  // V^T [B,H,DK,S]: dk rows, scatter 4x2B
#pragma unroll
        for (int r = 0; r < 4; ++r)
          vtd[(((size_t)(b * Hc + h) * DKc + dk0 + r) * Sc) + s] =
              __float2bfloat16(vv[r]);
      }
    }
  }
}

// ---------------- out projection (swapped): Y = oc @ Wo^T + bo ------------
// A = Wo (64 features), B = oc (128 s). float4 stores. flat grid 512.
__global__ __launch_bounds__(256, 2) void gemm_out(
    const __hip_bfloat16* __restrict__ X, const __hip_bfloat16* __restrict__ W,
    const float* __restrict__ bias, float* __restrict__ Y) {
  __shared__ __align__(16) __hip_bfloat16 As[2][64 * 64];   // Wo tile
  __shared__ __align__(16) __hip_bfloat16 Bs[2][128 * 64];  // oc tile
  const int tid = threadIdx.x;
  const int f = blockIdx.x, g = f >> 3;
  const int m0 = ((f & 7) * 4 + (g >> 4)) * 128;  // s block
  const int n0 = (g & 15) * 64;                    // feature block
  const int w = tid >> 6, lane = tid & 63, ln = lane & 15, quad = lane >> 4;
  const int wA = (w & 1) * 32, wB = (w >> 1) * 64;  // A-sub feats / B-sub s
  const int swz = ((lane & 7) ^ (lane >> 3)) * 8;
  const int rk0 = ln * 128 + ((quad ^ (ln & 7)) * 16);
  const int rk1 = ln * 128 + (((quad + 4) ^ (ln & 7)) * 16);
  const int aoff = (n0 + w * 16 + (lane >> 3)) * 1024 + swz;
  const int boff = (m0 + w * 32 + (lane >> 3)) * 1024 + swz;
  f32x4 acc[2][4] = {};  // [i: feat 16-blk][j: s 16-blk]

#define OSTAGE(KO, BI)                                                        \
  {                                                                           \
    _Pragma("unroll") for (int i = 0; i < 2; ++i)                             \
        lds_load16(&W[aoff + i * 8192 + (KO)],                                \
                   (char*)As[BI] + w * 2048 + lane * 16 + i * 1024);          \
    _Pragma("unroll") for (int i = 0; i < 4; ++i)                             \
        lds_load16(&X[boff + i * 8192 + (KO)],                                \
                   (char*)Bs[BI] + w * 4096 + lane * 16 + i * 1024);          \
  }

  OSTAGE(0, 0);
  for (int kb64 = 0; kb64 < 16; ++kb64) {
    const int bi = kb64 & 1;
    __syncthreads();
    if (kb64 + 1 < 16) OSTAGE((kb64 + 1) * 64, bi ^ 1);
    bf16x8 af[2][2], bf[4][2];
#pragma unroll
    for (int i = 0; i < 2; ++i) {
      af[i][0] = *(bf16x8*)((char*)As[bi] + wA * 128 + i * 2048 + rk0);
      af[i][1] = *(bf16x8*)((char*)As[bi] + wA * 128 + i * 2048 + rk1);
    }
#pragma unroll
    for (int j = 0; j < 4; ++j) {
      bf[j][0] = *(bf16x8*)((char*)Bs[bi] + wB * 128 + j * 2048 + rk0);
      bf[j][1] = *(bf16x8*)((char*)Bs[bi] + wB * 128 + j * 2048 + rk1);
    }
#pragma unroll
    for (int i = 0; i < 2; ++i)
#pragma unroll
      for (int j = 0; j < 4; ++j) {
        acc[i][j] = __builtin_amdgcn_mfma_f32_16x16x32_bf16(af[i][0], bf[j][0],
                                                            acc[i][j], 0, 0, 0);
        acc[i][j] = __builtin_amdgcn_mfma_f32_16x16x32_bf16(af[i][1], bf[j][1],
                                                            acc[i][j], 0, 0, 0);
      }
  }
#pragma unroll
  for (int i = 0; i < 2; ++i) {
    int nfb = n0 + wA + i * 16 + quad * 4;
    float4 b4 = *(const float4*)&bias[nfb];
#pragma unroll
    for (int j = 0; j < 4; ++j) {
      int sg = m0 + wB + j * 16 + ln;
      float4 st = {acc[i][j][0] + b4.x, acc[i][j][1] + b4.y,
                   acc[i][j][2] + b4.z, acc[i][j][3] + b4.w};
      *(float4*)&Y[(size_t)sg * Dc + nfb] = st;
    }
  }
}

// ---------------- flash attention (single pass, S^T, no-max) ----------------
// flat grid 512: XCD swizzle (4 bh per XCD -> K/V L2-resident). l via
// ones-MFMA. LDS: Ks[2]@0 16K, Vs[2]@16384 16K, Pt@32768 4x4608.
__global__ __launch_bounds__(256, 3) void flash_attn(
    const __hip_bfloat16* __restrict__ qh, const __hip_bfloat16* __restrict__ kh,
    const __hip_bfloat16* __restrict__ vt, const uint4* __restrict__ mb4,
    __hip_bfloat16* __restrict__ oc) {
  __shared__ __align__(16) char L[51200];
  const int tid = threadIdx.x;
  const int f = blockIdx.x, g = f >> 3;
  const int bh = (f & 7) * 4 + (g >> 4);  // 0..31
  const int q0 = (g & 15) * 128;
  const int b = bh >> 4, h = bh & 15;
  const int w = tid >> 6, lane = tid & 63, ln = lane & 15, quad = lane >> 4;
  const size_t base = (size_t)bh * Sc * DKc;
  const __hip_bfloat16* khb = kh + base;
  const __hip_bfloat16* vtb = vt + base;

  bf16x8 qf[2][2];
#pragma unroll
  for (int qt = 0; qt < 2; ++qt)
#pragma unroll
    for (int kc = 0; kc < 2; ++kc)
      qf[qt][kc] = *(const bf16x8*)&qh[base +
          (size_t)(q0 + w * 32 + qt * 16 + ln) * 64 + kc * 32 + quad * 8];

  bf16x8 onesA;
#pragma unroll
  for (int i = 0; i < 8; ++i) onesA[i] = (short)0x3F80;  // bf16 1.0

  const int swz = ((lane & 7) ^ (lane >> 3)) * 8;
  const int rk0 = ln * 128 + ((quad ^ (ln & 7)) * 16);
  const int rk1 = ln * 128 + (((quad + 4) ^ (ln & 7)) * 16);
  const int rPw = 32768 + w * 4608 + ln * 144 + quad * 8;
  const int rPb = 32768 + w * 4608 + ln * 144 + quad * 16;
  char* dmaL = L + w * 2048 + lane * 16;
  int koff = (w * 16 + (lane >> 3)) * 64 + swz;   // += 4096/tile
  int voff0 = (w * 16 + (lane >> 3)) * Sc + swz;  // += 64/tile
  int voff1 = voff0 + 8 * Sc;
  int midx0 = (q0 + w * 32 + ln) * 16;            // uint4 idx, += 1 / 2 tiles
  int midx1 = midx0 + 256;
  const int sh0 = quad * 4, sh1 = quad * 4 + 16;

#define KV_DMA(BI)                                                            \
  {                                                                           \
    lds_load16(khb + koff, dmaL + (BI)*8192);                                 \
    lds_load16(khb + koff + 512, dmaL + (BI)*8192 + 1024);                    \
    lds_load16(vtb + voff0, dmaL + 16384 + (BI)*8192);                        \
    lds_load16(vtb + voff1, dmaL + 16384 + (BI)*8192 + 1024);                 \
  }

  f32x4 Oacc[4][2] = {};
  f32x4 lacc[2] = {};
  KV_DMA(0);

#define FTILE(BUF, LO0, HI0, LO1, HI1)                                        \
  {                                                                           \
    bf16x8 kf[4][2];                                                          \
    _Pragma("unroll") for (int tt = 0; tt < 4; ++tt) {                        \
      kf[tt][0] = *(bf16x8*)(L + (BUF)*8192 + tt * 2048 + rk0);               \
      kf[tt][1] = *(bf16x8*)(L + (BUF)*8192 + tt * 2048 + rk1);               \
    }                                                                         \
    _Pragma("unroll") for (int qt = 0; qt < 2; ++qt) {                        \
      f32x4 s[4];                                                             \
      _Pragma("unroll") for (int tt = 0; tt < 4; ++tt) {                      \
        f32x4 z = {0.f, 0.f, 0.f, 0.f};                                       \
        z = __builtin_amdgcn_mfma_f32_16x16x32_bf16(kf[tt][0], qf[qt][0], z,  \
                                                    0, 0, 0);                 \
        s[tt] = __builtin_amdgcn_mfma_f32_16x16x32_bf16(kf[tt][1], qf[qt][1], \
                                                        z, 0, 0, 0);          \
      }                                                                       \
      unsigned lo = qt ? (LO1) : (LO0), hi = qt ? (HI1) : (HI0);              \
      _Pragma("unroll") for (int tt = 0; tt < 4; ++tt) {                      \
        unsigned word = (tt & 2) ? hi : lo;                                   \
        unsigned pre = word >> ((tt & 1) ? sh1 : sh0);                        \
        float p[4];                                                           \
        _Pragma("unroll") for (int r = 0; r < 4; ++r) {                       \
          float e = exp2_fast(s[tt][r]);                                      \
          p[r] = (pre & (1u << r)) ? e : 0.f;                                 \
        }                                                                     \
        uint2 pk = {pack_trunc(p[0], p[1]), pack_trunc(p[2], p[3])};          \
        *(uint2*)(L + rPw + qt * 2304 + tt * 32) = pk;                        \
      }                                                                       \
    }                                                                         \
    bf16x8 vf[4][2], pb[2][2];                                                \
    _Pragma("unroll") for (int dt = 0; dt < 4; ++dt) {                        \
      vf[dt][0] = *(bf16x8*)(L + 16384 + (BUF)*8192 + dt * 2048 + rk0);       \
      vf[dt][1] = *(bf16x8*)(L + 16384 + (BUF)*8192 + dt * 2048 + rk1);       \
    }                                                                         \
    _Pragma("unroll") for (int qt = 0; qt < 2; ++qt) {                        \
      pb[qt][0] = *(bf16x8*)(L + rPb + qt * 2304);                            \
      pb[qt][1] = *(bf16x8*)(L + rPb + qt * 2304 + 64);                       \
    }                                                                         \
    _Pragma("unroll") for (int qt = 0; qt < 2; ++qt) {                        \
      lacc[qt] = __builtin_amdgcn_mfma_f32_16x16x32_bf16(onesA, pb[qt][0],    \
                                                         lacc[qt], 0, 0, 0);  \
      lacc[qt] = __builtin_amdgcn_mfma_f32_16x16x32_bf16(onesA, pb[qt][1],    \
                                                         lacc[qt], 0, 0, 0);  \
    }                                                                         \
    _Pragma("unroll") for (int dt = 0; dt < 4; ++dt)                          \
        _Pragma("unroll") for (int qt = 0; qt < 2; ++qt) {                    \
      Oacc[dt][qt] = __builtin_amdgcn_mfma_f32_16x16x32_bf16(                 \
          vf[dt][0], pb[qt][0], Oacc[dt][qt], 0, 0, 0);                       \
      Oacc[dt][qt] = __builtin_amdgcn_mfma_f32_16x16x32_bf16(                 \
          vf[dt][1], pb[qt][1], Oacc[dt][qt], 0, 0, 0);                       \
    }                                                                         \
  }

  for (int it2 = 0; it2 < 16; ++it2) {
    __syncthreads();
    uint4 mq0 = mb4[midx0], mq1 = mb4[midx1];
    ++midx0; ++midx1;
    koff += 4096; voff0 += 64; voff1 += 64;
    KV_DMA(1);
    FTILE(0, mq0.x, mq0.y, mq1.x, mq1.y);
    __syncthreads();
    if (it2 < 15) {
      koff += 4096; voff0 += 64; voff1 += 64;
      KV_DMA(0);
    }
    FTILE(1, mq0.z, mq0.w, mq1.z, mq1.w);
  }

  // epilogue: linv from ones-MFMA (all rows identical); transpose via wave
  // scratch -> coalesced bf16x8 stores.
  float linv[2];
#pragma unroll
  for (int qt = 0; qt < 2; ++qt)
    linv[qt] = 1.f / fmaxf(lacc[qt][0], 1e-30f);
#pragma unroll
  for (int dt = 0; dt < 4; ++dt)
#pragma unroll
    for (int qt = 0; qt < 2; ++qt) {
      f32x4 o = Oacc[dt][qt];
      uint2 pk = {pack2bf(o[0] * linv[qt], o[1] * linv[qt]),
                  pack2bf(o[2] * linv[qt], o[3] * linv[qt])};
      *(uint2*)(L + rPw + qt * 2304 + dt * 32) = pk;
    }
  __builtin_amdgcn_s_waitcnt(0);
#pragma unroll
  for (int chunk = 0; chunk < 4; ++chunk) {
    int row = chunk * 8 + (lane >> 3);
    bf16x8 val = *(bf16x8*)(L + 32768 + w * 4608 + row * 144 + (lane & 7) * 16);
    int s = q0 + w * 32 + row;
    *(bf16x8*)&oc[(size_t)(b * Sc + s) * Dc + h * 64 + (lane & 7) * 8] = val;
  }
}

extern "C" void kernel_launch(void* const* d_in, const int* in_sizes, int n_in,
                              void* d_out, int out_size, void* d_ws, size_t ws_size,
                              hipStream_t stream) {
  const float* q  = (const float*)d_in[0];
  const float* k  = (const float*)d_in[1];
  const float* v  = (const float*)d_in[2];
  const int* mask = (const int*)d_in[3];
  const float* Wq = (const float*)d_in[4];
  const float* bq = (const float*)d_in[5];
  const float* Wk = (const float*)d_in[6];
  const float* bk = (const float*)d_in[7];
  const float* Wv = (const float*)d_in[8];
  const float* bv = (const float*)d_in[9];
  const float* Wo = (const float*)d_in[10];
  const float* bo = (const float*)d_in[11];

  char* ws = (char*)d_ws;
  const size_t MB = 1024 * 1024;
  __hip_bfloat16* qb   = (__hip_bfloat16*)(ws + 0 * MB);
  __hip_bfloat16* kb   = (__hip_bfloat16*)(ws + 8 * MB);
  __hip_bfloat16* vb   = (__hip_bfloat16*)(ws + 16 * MB);
  __hip_bfloat16* Wcat = (__hip_bfloat16*)(ws + 24 * MB);  // Wq|Wk|Wv
  __hip_bfloat16* Wob  = (__hip_bfloat16*)(ws + 30 * MB);
  uint4*          mb4  = (uint4*)(ws + 32 * MB);
  __hip_bfloat16* qhd  = (__hip_bfloat16*)(ws + 33 * MB);
  __hip_bfloat16* khd  = (__hip_bfloat16*)(ws + 41 * MB);
  __hip_bfloat16* vtd  = (__hip_bfloat16*)(ws + 49 * MB);
  __hip_bfloat16* oc   = (__hip_bfloat16*)(ws + 57 * MB);

  prep<<<32768, 256, 0, stream>>>(q, k, v, mask, Wq, Wk, Wv, Wo, ws);
  proj_qkv<<<768, 256, 0, stream>>>(qb, kb, vb, Wcat, bq, bk, bv, qhd, khd, vtd);
  flash_attn<<<512, 256, 0, stream>>>(qhd, khd, vtd, mb4, oc);
  gemm_out<<<512, 256, 0, stream>>>(oc, Wob, bo, (float*)d_out);
}

// Round 8
// 244.473 us; speedup vs baseline: 1.0095x; 1.0095x over previous
//
#include <hip/hip_runtime.h>
#include <hip/hip_bf16.h>

// MultiHeadAttention: B=2, S=2048, D=1024, H=16, DK=64
// Round 8: proj_qkv rebuilt as BK=32 double-buffered DMA GEMM (latency no
// longer fully exposed per K-iter; 32KB LDS keeps 3 blocks/CU, grid 768 fills
// exactly). V-projection uses swapped MFMA operands (A=X,B=W) so the V^T
// epilogue is packed uint2 stores. prep/flash/gemm_out unchanged from R7.
// Workspace: qb@0 kb@8 vb@16 Wcat@24(6M) Wob@30 mbits@32 qhd@33 khd@41
//            vtd@49 oc@57  (MiB offsets)

using bf16x8 = __attribute__((ext_vector_type(8))) short;
using f32x4  = __attribute__((ext_vector_type(4))) float;

constexpr int Bc = 2, Sc = 2048, Dc = 1024, Hc = 16, DKc = 64;
constexpr int Mc = Bc * Sc;  // 4096
#define QSCALE 0.18033688011112042f  // log2(e)/sqrt(DK), folded into Q proj

__device__ __forceinline__ void lds_load16(const void* g, void* l) {
  __builtin_amdgcn_global_load_lds(
      (const __attribute__((address_space(1))) unsigned int*)g,
      (__attribute__((address_space(3))) unsigned int*)l, 16, 0, 0);
}

#if __has_builtin(__builtin_amdgcn_exp2f)
__device__ __forceinline__ float exp2_fast(float x) { return __builtin_amdgcn_exp2f(x); }
#else
__device__ __forceinline__ float exp2_fast(float x) {
  float r;
  asm("v_exp_f32 %0, %1\n\ts_nop 0" : "=v"(r) : "v"(x));
  return r;
}
#endif

// truncating bf16x2 pack: [hi16(b) : hi16(a)] — one v_perm_b32
__device__ __forceinline__ unsigned pack_trunc(float a, float b) {
  return __builtin_amdgcn_perm(__float_as_uint(b), __float_as_uint(a), 0x07060302u);
}

// RNE pack (epilogues)
__device__ __forceinline__ unsigned pack2bf(float a, float b) {
  union { __hip_bfloat16 h; unsigned short s; } ua, ub;
  ua.h = __float2bfloat16(a);
  ub.h = __float2bfloat16(b);
  return (unsigned)ua.s | ((unsigned)ub.s << 16);
}

// ---------------- prep: fused casts + mask pack ----------------
__global__ void prep(const float* __restrict__ q, const float* __restrict__ k,
                     const float* __restrict__ v, const int* __restrict__ mask,
                     const float* __restrict__ Wq, const float* __restrict__ Wk,
                     const float* __restrict__ Wv, const float* __restrict__ Wo,
                     char* __restrict__ ws) {
  const size_t MB = 1024 * 1024;
  int blk = blockIdx.x;
  if (blk < 12288) {
    int which = blk >> 12;
    int i = (((blk & 4095) << 8) + threadIdx.x) * 4;
    const float* s = which == 0 ? q : (which == 1 ? k : v);
    __hip_bfloat16* d = (__hip_bfloat16*)(ws + (size_t)which * 8 * MB);
    float4 x = *(const float4*)&s[i];
    uint2 pk = {pack2bf(x.x, x.y), pack2bf(x.z, x.w)};
    *(uint2*)&d[i] = pk;
  } else if (blk < 16384) {
    int bb = blk - 12288;
    int which = bb >> 10;
    int i = (((bb & 1023) << 8) + threadIdx.x) * 4;
    const float* s = which == 0 ? Wq : (which == 1 ? Wk : (which == 2 ? Wv : Wo));
    __hip_bfloat16* d = which < 3 ? (__hip_bfloat16*)(ws + (24 + 2 * which) * MB)
                                  : (__hip_bfloat16*)(ws + 30 * MB);
    float4 x = *(const float4*)&s[i];
    uint2 pk = {pack2bf(x.x, x.y), pack2bf(x.z, x.w)};
    *(uint2*)&d[i] = pk;
  } else {
    int i = ((blk - 16384) << 8) + threadIdx.x;
    unsigned long long bal = __ballot(mask[i] != 0);
    if ((threadIdx.x & 63) == 0)
      ((unsigned long long*)(ws + 32 * MB))[i >> 6] = bal;
  }
}

// ---------------- fused QKV projection (BK=32 dbuf) ----------------
// A = Wcat (features), B = X (s). Q/K: mfma(A=W,B=X) -> C col=s,row=feat ->
// packed dk stores. V: mfma(A=X,B=W) -> C col=feat,row=s -> packed s stores
// into V^T [B,H,DK,S]. flat grid 768, XCD swizzle, 3 blocks/CU.
__global__ __launch_bounds__(256, 3) void proj_qkv(
    const __hip_bfloat16* __restrict__ qb, const __hip_bfloat16* __restrict__ kb,
    const __hip_bfloat16* __restrict__ vb, const __hip_bfloat16* __restrict__ Wcat,
    const float* __restrict__ bq, const float* __restrict__ bk,
    const float* __restrict__ bv, __hip_bfloat16* __restrict__ qhd,
    __hip_bfloat16* __restrict__ khd, __hip_bfloat16* __restrict__ vtd) {
  __shared__ __align__(16) __hip_bfloat16 As[2][128 * 32];  // W tiles, 8KB each
  __shared__ __align__(16) __hip_bfloat16 Bs[2][128 * 32];  // X tiles
  const int tid = threadIdx.x;
  const int f = blockIdx.x, g = f >> 3;
  const int m0 = ((f & 7) * 4 + g / 24) * 128;  // s block
  const int n0 = (g % 24) * 128;                // feature block (0..3072)
  const int which = n0 >> 10, nl0 = n0 & 1023;
  const __hip_bfloat16* X = which == 0 ? qb : (which == 1 ? kb : vb);
  const float* bias = which == 0 ? bq : (which == 1 ? bk : bv);
  const int w = tid >> 6, lane = tid & 63, ln = lane & 15, quad = lane >> 4;
  // staging: local row rl = w*32 + j*16 + (lane>>2); 8-el group cg = lane&3,
  // swizzled cg' = cg ^ (rl&3) with rl&3 == (lane>>2)&3
  const int rl = w * 32 + (lane >> 2);
  const int sw8 = ((lane & 3) ^ ((lane >> 2) & 3)) * 8;
  const int aoff = (n0 + rl) * 1024 + sw8;
  const int boff = (m0 + rl) * 1024 + sw8;
  char* aDst = (char*)As + w * 2048 + lane * 16;
  char* bDst = (char*)Bs + w * 2048 + lane * 16;
  // frag read: row r = sub + i*16 + ln; addr = r*64 + ((quad^(ln&3))*16)
  const int rkq = (quad ^ (ln & 3)) * 16;
  const int rA0 = ((w >> 1) * 64 + ln) * 64 + rkq;   // + i*1024
  const int rB0 = ((w & 1) * 64 + ln) * 64 + rkq;    // + j*1024
  f32x4 acc[4][4] = {};  // [i: feature 16-blk][j: s 16-blk]

#define PSTAGE(KO, BI)                                                        \
  {                                                                           \
    lds_load16(&Wcat[aoff + (KO)], aDst + (BI)*8192);                         \
    lds_load16(&Wcat[aoff + 16384 + (KO)], aDst + (BI)*8192 + 1024);          \
    lds_load16(&X[boff + (KO)], bDst + (BI)*8192);                            \
    lds_load16(&X[boff + 16384 + (KO)], bDst + (BI)*8192 + 1024);             \
  }

  PSTAGE(0, 0);
  if (which == 2) {
    for (int kb32 = 0; kb32 < 32; ++kb32) {
      const int bi = kb32 & 1;
      __syncthreads();
      if (kb32 < 31) PSTAGE((kb32 + 1) * 32, bi ^ 1);
      bf16x8 af[4], bf[4];
#pragma unroll
      for (int i = 0; i < 4; ++i)
        af[i] = *(bf16x8*)((char*)As + bi * 8192 + rA0 + i * 1024);
#pragma unroll
      for (int j = 0; j < 4; ++j)
        bf[j] = *(bf16x8*)((char*)Bs + bi * 8192 + rB0 + j * 1024);
#pragma unroll
      for (int i = 0; i < 4; ++i)
#pragma unroll
        for (int j = 0; j < 4; ++j)  // swapped: A=X -> C rows = s
          acc[i][j] = __builtin_amdgcn_mfma_f32_16x16x32_bf16(bf[j], af[i],
                                                              acc[i][j], 0, 0, 0);
    }
  } else {
    for (int kb32 = 0; kb32 < 32; ++kb32) {
      const int bi = kb32 & 1;
      __syncthreads();
      if (kb32 < 31) PSTAGE((kb32 + 1) * 32, bi ^ 1);
      bf16x8 af[4], bf[4];
#pragma unroll
      for (int i = 0; i < 4; ++i)
        af[i] = *(bf16x8*)((char*)As + bi * 8192 + rA0 + i * 1024);
#pragma unroll
      for (int j = 0; j < 4; ++j)
        bf[j] = *(bf16x8*)((char*)Bs + bi * 8192 + rB0 + j * 1024);
#pragma unroll
      for (int i = 0; i < 4; ++i)
#pragma unroll
        for (int j = 0; j < 4; ++j)  // A=W -> C rows = features
          acc[i][j] = __builtin_amdgcn_mfma_f32_16x16x32_bf16(af[i], bf[j],
                                                              acc[i][j], 0, 0, 0);
    }
  }

  const int wA = (w >> 1) * 64, wB = (w & 1) * 64;
  if (which == 2) {
    // C col(ln)=feature, row(quad*4+r)=s -> 4 consecutive s per lane
#pragma unroll
    for (int i = 0; i < 4; ++i) {
      int nf = nl0 + wA + i * 16 + ln;
      int h = nf >> 6, dk = nf & 63;
      float bb = bias[nf];
#pragma unroll
      for (int j = 0; j < 4; ++j) {
        int sb = m0 + wB + j * 16 + quad * 4;
        int b = sb >> 11, s = sb & 2047;
        float vv[4] = {acc[i][j][0] + bb, acc[i][j][1] + bb,
                       acc[i][j][2] + bb, acc[i][j][3] + bb};
        uint2 pk = {pack2bf(vv[0], vv[1]), pack2bf(vv[2], vv[3])};
        *(uint2*)&vtd[(((size_t)(b * Hc + h) * DKc + dk) * Sc) + s] = pk;
      }
    }
  } else {
    // C col(ln)=s, row(quad*4+r)=feature -> 4 consecutive dk per lane
#pragma unroll
    for (int i = 0; i < 4; ++i) {
      int nfb = nl0 + wA + i * 16 + quad * 4;
      float4 b4 = *(const float4*)&bias[nfb];
      int h = nfb >> 6, dk0 = nfb & 63;
#pragma unroll
      for (int j = 0; j < 4; ++j) {
        int sg = m0 + wB + j * 16 + ln;
        int b = sg >> 11, s = sg & 2047;
        float vv[4] = {acc[i][j][0] + b4.x, acc[i][j][1] + b4.y,
                       acc[i][j][2] + b4.z, acc[i][j][3] + b4.w};
        if (which == 0) {
          uint2 pk = {pack2bf(vv[0] * QSCALE, vv[1] * QSCALE),
                      pack2bf(vv[2] * QSCALE, vv[3] * QSCALE)};
          *(uint2*)&qhd[(((size_t)(b * Hc + h) * Sc + s) * DKc) + dk0] = pk;
        } else {
          uint2 pk = {pack2bf(vv[0], vv[1]), pack2bf(vv[2], vv[3])};
          *(uint2*)&khd[(((size_t)(b * Hc + h) * Sc + s) * DKc) + dk0] = pk;
        }
      }
    }
  }
}

// ---------------- out projection (swapped): Y = oc @ Wo^T + bo ------------
__global__ __launch_bounds__(256, 2) void gemm_out(
    const __hip_bfloat16* __restrict__ X, const __hip_bfloat16* __restrict__ W,
    const float* __restrict__ bias, float* __restrict__ Y) {
  __shared__ __align__(16) __hip_bfloat16 As[2][64 * 64];   // Wo tile
  __shared__ __align__(16) __hip_bfloat16 Bs[2][128 * 64];  // oc tile
  const int tid = threadIdx.x;
  const int f = blockIdx.x, g = f >> 3;
  const int m0 = ((f & 7) * 4 + (g >> 4)) * 128;  // s block
  const int n0 = (g & 15) * 64;                    // feature block
  const int w = tid >> 6, lane = tid & 63, ln = lane & 15, quad = lane >> 4;
  const int wA = (w & 1) * 32, wB = (w >> 1) * 64;
  const int swz = ((lane & 7) ^ (lane >> 3)) * 8;
  const int rk0 = ln * 128 + ((quad ^ (ln & 7)) * 16);
  const int rk1 = ln * 128 + (((quad + 4) ^ (ln & 7)) * 16);
  const int aoff = (n0 + w * 16 + (lane >> 3)) * 1024 + swz;
  const int boff = (m0 + w * 32 + (lane >> 3)) * 1024 + swz;
  f32x4 acc[2][4] = {};

#define OSTAGE(KO, BI)                                                        \
  {                                                                           \
    _Pragma("unroll") for (int i = 0; i < 2; ++i)                             \
        lds_load16(&W[aoff + i * 8192 + (KO)],                                \
                   (char*)As[BI] + w * 2048 + lane * 16 + i * 1024);          \
    _Pragma("unroll") for (int i = 0; i < 4; ++i)                             \
        lds_load16(&X[boff + i * 8192 + (KO)],                                \
                   (char*)Bs[BI] + w * 4096 + lane * 16 + i * 1024);          \
  }

  OSTAGE(0, 0);
  for (int kb64 = 0; kb64 < 16; ++kb64) {
    const int bi = kb64 & 1;
    __syncthreads();
    if (kb64 + 1 < 16) OSTAGE((kb64 + 1) * 64, bi ^ 1);
    bf16x8 af[2][2], bf[4][2];
#pragma unroll
    for (int i = 0; i < 2; ++i) {
      af[i][0] = *(bf16x8*)((char*)As[bi] + wA * 128 + i * 2048 + rk0);
      af[i][1] = *(bf16x8*)((char*)As[bi] + wA * 128 + i * 2048 + rk1);
    }
#pragma unroll
    for (int j = 0; j < 4; ++j) {
      bf[j][0] = *(bf16x8*)((char*)Bs[bi] + wB * 128 + j * 2048 + rk0);
      bf[j][1] = *(bf16x8*)((char*)Bs[bi] + wB * 128 + j * 2048 + rk1);
    }
#pragma unroll
    for (int i = 0; i < 2; ++i)
#pragma unroll
      for (int j = 0; j < 4; ++j) {
        acc[i][j] = __builtin_amdgcn_mfma_f32_16x16x32_bf16(af[i][0], bf[j][0],
                                                            acc[i][j], 0, 0, 0);
        acc[i][j] = __builtin_amdgcn_mfma_f32_16x16x32_bf16(af[i][1], bf[j][1],
                                                            acc[i][j], 0, 0, 0);
      }
  }
#pragma unroll
  for (int i = 0; i < 2; ++i) {
    int nfb = n0 + wA + i * 16 + quad * 4;
    float4 b4 = *(const float4*)&bias[nfb];
#pragma unroll
    for (int j = 0; j < 4; ++j) {
      int sg = m0 + wB + j * 16 + ln;
      float4 st = {acc[i][j][0] + b4.x, acc[i][j][1] + b4.y,
                   acc[i][j][2] + b4.z, acc[i][j][3] + b4.w};
      *(float4*)&Y[(size_t)sg * Dc + nfb] = st;
    }
  }
}

// ---------------- flash attention (single pass, S^T, no-max) ----------------
__global__ __launch_bounds__(256, 3) void flash_attn(
    const __hip_bfloat16* __restrict__ qh, const __hip_bfloat16* __restrict__ kh,
    const __hip_bfloat16* __restrict__ vt, const uint4* __restrict__ mb4,
    __hip_bfloat16* __restrict__ oc) {
  __shared__ __align__(16) char L[51200];
  const int tid = threadIdx.x;
  const int f = blockIdx.x, g = f >> 3;
  const int bh = (f & 7) * 4 + (g >> 4);  // 0..31
  const int q0 = (g & 15) * 128;
  const int b = bh >> 4, h = bh & 15;
  const int w = tid >> 6, lane = tid & 63, ln = lane & 15, quad = lane >> 4;
  const size_t base = (size_t)bh * Sc * DKc;
  const __hip_bfloat16* khb = kh + base;
  const __hip_bfloat16* vtb = vt + base;

  bf16x8 qf[2][2];
#pragma unroll
  for (int qt = 0; qt < 2; ++qt)
#pragma unroll
    for (int kc = 0; kc < 2; ++kc)
      qf[qt][kc] = *(const bf16x8*)&qh[base +
          (size_t)(q0 + w * 32 + qt * 16 + ln) * 64 + kc * 32 + quad * 8];

  bf16x8 onesA;
#pragma unroll
  for (int i = 0; i < 8; ++i) onesA[i] = (short)0x3F80;  // bf16 1.0

  const int swz = ((lane & 7) ^ (lane >> 3)) * 8;
  const int rk0 = ln * 128 + ((quad ^ (ln & 7)) * 16);
  const int rk1 = ln * 128 + (((quad + 4) ^ (ln & 7)) * 16);
  const int rPw = 32768 + w * 4608 + ln * 144 + quad * 8;
  const int rPb = 32768 + w * 4608 + ln * 144 + quad * 16;
  char* dmaL = L + w * 2048 + lane * 16;
  int koff = (w * 16 + (lane >> 3)) * 64 + swz;
  int voff0 = (w * 16 + (lane >> 3)) * Sc + swz;
  int voff1 = voff0 + 8 * Sc;
  int midx0 = (q0 + w * 32 + ln) * 16;
  int midx1 = midx0 + 256;
  const int sh0 = quad * 4, sh1 = quad * 4 + 16;

#define KV_DMA(BI)                                                            \
  {                                                                           \
    lds_load16(khb + koff, dmaL + (BI)*8192);                                 \
    lds_load16(khb + koff + 512, dmaL + (BI)*8192 + 1024);                    \
    lds_load16(vtb + voff0, dmaL + 16384 + (BI)*8192);                        \
    lds_load16(vtb + voff1, dmaL + 16384 + (BI)*8192 + 1024);                 \
  }

  f32x4 Oacc[4][2] = {};
  f32x4 lacc[2] = {};
  KV_DMA(0);

#define FTILE(BUF, LO0, HI0, LO1, HI1)                                        \
  {                                                                           \
    bf16x8 kf[4][2];                                                          \
    _Pragma("unroll") for (int tt = 0; tt < 4; ++tt) {                        \
      kf[tt][0] = *(bf16x8*)(L + (BUF)*8192 + tt * 2048 + rk0);               \
      kf[tt][1] = *(bf16x8*)(L + (BUF)*8192 + tt * 2048 + rk1);               \
    }                                                                         \
    _Pragma("unroll") for (int qt = 0; qt < 2; ++qt) {                        \
      f32x4 s[4];                                                             \
      _Pragma("unroll") for (int tt = 0; tt < 4; ++tt) {                      \
        f32x4 z = {0.f, 0.f, 0.f, 0.f};                                       \
        z = __builtin_amdgcn_mfma_f32_16x16x32_bf16(kf[tt][0], qf[qt][0], z,  \
                                                    0, 0, 0);                 \
        s[tt] = __builtin_amdgcn_mfma_f32_16x16x32_bf16(kf[tt][1], qf[qt][1], \
                                                        z, 0, 0, 0);          \
      }                                                                       \
      unsigned lo = qt ? (LO1) : (LO0), hi = qt ? (HI1) : (HI0);              \
      _Pragma("unroll") for (int tt = 0; tt < 4; ++tt) {                      \
        unsigned word = (tt & 2) ? hi : lo;                                   \
        unsigned pre = word >> ((tt & 1) ? sh1 : sh0);                        \
        float p[4];                                                           \
        _Pragma("unroll") for (int r = 0; r < 4; ++r) {                       \
          float e = exp2_fast(s[tt][r]);                                      \
          p[r] = (pre & (1u << r)) ? e : 0.f;                                 \
        }                                                                     \
        uint2 pk = {pack_trunc(p[0], p[1]), pack_trunc(p[2], p[3])};          \
        *(uint2*)(L + rPw + qt * 2304 + tt * 32) = pk;                        \
      }                                                                       \
    }                                                                         \
    bf16x8 vf[4][2], pb[2][2];                                                \
    _Pragma("unroll") for (int dt = 0; dt < 4; ++dt) {                        \
      vf[dt][0] = *(bf16x8*)(L + 16384 + (BUF)*8192 + dt * 2048 + rk0);       \
      vf[dt][1] = *(bf16x8*)(L + 16384 + (BUF)*8192 + dt * 2048 + rk1);       \
    }                                                                         \
    _Pragma("unroll") for (int qt = 0; qt < 2; ++qt) {                        \
      pb[qt][0] = *(bf16x8*)(L + rPb + qt * 2304);                            \
      pb[qt][1] = *(bf16x8*)(L + rPb + qt * 2304 + 64);                       \
    }                                                                         \
    _Pragma("unroll") for (int qt = 0; qt < 2; ++qt) {                        \
      lacc[qt] = __builtin_amdgcn_mfma_f32_16x16x32_bf16(onesA, pb[qt][0],    \
                                                         lacc[qt], 0, 0, 0);  \
      lacc[qt] = __builtin_amdgcn_mfma_f32_16x16x32_bf16(onesA, pb[qt][1],    \
                                                         lacc[qt], 0, 0, 0);  \
    }                                                                         \
    _Pragma("unroll") for (int dt = 0; dt < 4; ++dt)                          \
        _Pragma("unroll") for (int qt = 0; qt < 2; ++qt) {                    \
      Oacc[dt][qt] = __builtin_amdgcn_mfma_f32_16x16x32_bf16(                 \
          vf[dt][0], pb[qt][0], Oacc[dt][qt], 0, 0, 0);                       \
      Oacc[dt][qt] = __builtin_amdgcn_mfma_f32_16x16x32_bf16(                 \
          vf[dt][1], pb[qt][1], Oacc[dt][qt], 0, 0, 0);                       \
    }                                                                         \
  }

  for (int it2 = 0; it2 < 16; ++it2) {
    __syncthreads();
    uint4 mq0 = mb4[midx0], mq1 = mb4[midx1];
    ++midx0; ++midx1;
    koff += 4096; voff0 += 64; voff1 += 64;
    KV_DMA(1);
    FTILE(0, mq0.x, mq0.y, mq1.x, mq1.y);
    __syncthreads();
    if (it2 < 15) {
      koff += 4096; voff0 += 64; voff1 += 64;
      KV_DMA(0);
    }
    FTILE(1, mq0.z, mq0.w, mq1.z, mq1.w);
  }

  float linv[2];
#pragma unroll
  for (int qt = 0; qt < 2; ++qt)
    linv[qt] = 1.f / fmaxf(lacc[qt][0], 1e-30f);
#pragma unroll
  for (int dt = 0; dt < 4; ++dt)
#pragma unroll
    for (int qt = 0; qt < 2; ++qt) {
      f32x4 o = Oacc[dt][qt];
      uint2 pk = {pack2bf(o[0] * linv[qt], o[1] * linv[qt]),
                  pack2bf(o[2] * linv[qt], o[3] * linv[qt])};
      *(uint2*)(L + rPw + qt * 2304 + dt * 32) = pk;
    }
  __builtin_amdgcn_s_waitcnt(0);
#pragma unroll
  for (int chunk = 0; chunk < 4; ++chunk) {
    int row = chunk * 8 + (lane >> 3);
    bf16x8 val = *(bf16x8*)(L + 32768 + w * 4608 + row * 144 + (lane & 7) * 16);
    int s = q0 + w * 32 + row;
    *(bf16x8*)&oc[(size_t)(b * Sc + s) * Dc + h * 64 + (lane & 7) * 8] = val;
  }
}

extern "C" void kernel_launch(void* const* d_in, const int* in_sizes, int n_in,
                              void* d_out, int out_size, void* d_ws, size_t ws_size,
                              hipStream_t stream) {
  const float* q  = (const float*)d_in[0];
  const float* k  = (const float*)d_in[1];
  const float* v  = (const float*)d_in[2];
  const int* mask = (const int*)d_in[3];
  const float* Wq = (const float*)d_in[4];
  const float* bq = (const float*)d_in[5];
  const float* Wk = (const float*)d_in[6];
  const float* bk = (const float*)d_in[7];
  const float* Wv = (const float*)d_in[8];
  const float* bv = (const float*)d_in[9];
  const float* Wo = (const float*)d_in[10];
  const float* bo = (const float*)d_in[11];

  char* ws = (char*)d_ws;
  const size_t MB = 1024 * 1024;
  __hip_bfloat16* qb   = (__hip_bfloat16*)(ws + 0 * MB);
  __hip_bfloat16* kb   = (__hip_bfloat16*)(ws + 8 * MB);
  __hip_bfloat16* vb   = (__hip_bfloat16*)(ws + 16 * MB);
  __hip_bfloat16* Wcat = (__hip_bfloat16*)(ws + 24 * MB);  // Wq|Wk|Wv
  __hip_bfloat16* Wob  = (__hip_bfloat16*)(ws + 30 * MB);
  uint4*          mb4  = (uint4*)(ws + 32 * MB);
  __hip_bfloat16* qhd  = (__hip_bfloat16*)(ws + 33 * MB);
  __hip_bfloat16* khd  = (__hip_bfloat16*)(ws + 41 * MB);
  __hip_bfloat16* vtd  = (__hip_bfloat16*)(ws + 49 * MB);
  __hip_bfloat16* oc   = (__hip_bfloat16*)(ws + 57 * MB);

  prep<<<32768, 256, 0, stream>>>(q, k, v, mask, Wq, Wk, Wv, Wo, ws);
  proj_qkv<<<768, 256, 0, stream>>>(qb, kb, vb, Wcat, bq, bk, bv, qhd, khd, vtd);
  flash_attn<<<512, 256, 0, stream>>>(qhd, khd, vtd, mb4, oc);
  gemm_out<<<512, 256, 0, stream>>>(oc, Wob, bo, (float*)d_out);
}